// Round 1
// baseline (444.236 us; speedup 1.0000x reference)
//
#include <hip/hip_runtime.h>

// Problem constants (fixed by setup_inputs)
#define BATCH 32
#define NCAND 512
#define HH 64
#define WW 64
#define KSEL 256
#define HW (HH * WW)          // 4096 floats per image
#define OUT_H (HH - 2)        // 62
#define OUT_W (WW - 2)        // 62
#define NOUT (OUT_H * OUT_W)  // 3844

// ---------------------------------------------------------------------------
// Kernel 1: per-image curvature score.
// One block (256 threads) per (b,n) image. Stage 64x64 f32 tile in LDS,
// compute 3x3 VALID conv per output pixel in f64 (weights are exact in f32),
// abs, accumulate in f64, block-reduce, write score.
// ---------------------------------------------------------------------------
__global__ __launch_bounds__(256) void score_kernel(
    const float* __restrict__ x, const float* __restrict__ w,
    double* __restrict__ p) {
  __shared__ float tile[HH][WW];          // 16 KiB
  __shared__ double partial[4];

  const int img = blockIdx.x;             // b*NCAND + n
  const int tid = threadIdx.x;

  // Coalesced float4 staging: 1024 float4 / 256 threads = 4 each.
  const float4* src4 = (const float4*)(x + (size_t)img * HW);
  float4* t4 = (float4*)&tile[0][0];
#pragma unroll
  for (int i = 0; i < 4; ++i) t4[i * 256 + tid] = src4[i * 256 + tid];

  // Weights (uniform loads; values exact in f32: -1/16, 5/16, -1)
  const double w00 = w[0], w01 = w[1], w02 = w[2];
  const double w10 = w[3], w11 = w[4], w12 = w[5];
  const double w20 = w[6], w21 = w[7], w22 = w[8];

  __syncthreads();

  double acc = 0.0;
#pragma unroll
  for (int it = 0; it < 16; ++it) {
    const int o = it * 256 + tid;
    if (o < NOUT) {
      const int i = o / OUT_W;
      const int j = o - i * OUT_W;
      double s;
      s  = (double)tile[i    ][j] * w00 + (double)tile[i    ][j + 1] * w01 + (double)tile[i    ][j + 2] * w02;
      s += (double)tile[i + 1][j] * w10 + (double)tile[i + 1][j + 1] * w11 + (double)tile[i + 1][j + 2] * w12;
      s += (double)tile[i + 2][j] * w20 + (double)tile[i + 2][j + 1] * w21 + (double)tile[i + 2][j + 2] * w22;
      acc += fabs(s);
    }
  }

  // Wave (64-lane) butterfly-free down-reduce, then cross-wave via LDS.
#pragma unroll
  for (int off = 32; off > 0; off >>= 1) acc += __shfl_down(acc, off, 64);
  if ((tid & 63) == 0) partial[tid >> 6] = acc;
  __syncthreads();
  if (tid == 0) p[img] = partial[0] + partial[1] + partial[2] + partial[3];
}

// ---------------------------------------------------------------------------
// Kernel 2: per-batch exact top-k ordering via rank computation.
// rank(n) = #{m : p[m] > p[n]  or  (p[m] == p[n] and m < n)}.
// rank < K  ->  idx[b*K + rank] = n  (descending order, index-stable ties —
// exactly lax.top_k semantics).
// ---------------------------------------------------------------------------
__global__ __launch_bounds__(512) void rank_kernel(
    const double* __restrict__ p, int* __restrict__ idx) {
  __shared__ double sp[NCAND];            // 4 KiB
  const int b = blockIdx.x;
  const int n = threadIdx.x;
  sp[n] = p[(size_t)b * NCAND + n];
  __syncthreads();
  const double pn = sp[n];
  int rank = 0;
#pragma unroll 8
  for (int m = 0; m < NCAND; ++m) {
    const double pm = sp[m];              // broadcast read, no conflict
    rank += (pm > pn) || (pm == pn && m < n);
  }
  if (rank < KSEL) idx[b * KSEL + rank] = n;
}

// ---------------------------------------------------------------------------
// Kernel 3: gather selected images. One block per output slot (b,r);
// coalesced float4 copy of 16 KiB.
// ---------------------------------------------------------------------------
__global__ __launch_bounds__(256) void gather_kernel(
    const float* __restrict__ x, const int* __restrict__ idx,
    float* __restrict__ out) {
  const int o = blockIdx.x;               // b*KSEL + r
  const int b = o / KSEL;
  const int n = idx[o];                   // uniform load
  const float4* src = (const float4*)(x + ((size_t)b * NCAND + n) * HW);
  float4* dst = (float4*)(out + (size_t)o * HW);
  const int tid = threadIdx.x;
#pragma unroll
  for (int i = 0; i < 4; ++i) dst[i * 256 + tid] = src[i * 256 + tid];
}

extern "C" void kernel_launch(void* const* d_in, const int* in_sizes, int n_in,
                              void* d_out, int out_size, void* d_ws,
                              size_t ws_size, hipStream_t stream) {
  const float* x = (const float*)d_in[0];
  const float* w = (const float*)d_in[1];
  float* out = (float*)d_out;

  // Workspace layout: scores (16384 f64 = 128 KiB) then idx (8192 i32 = 32 KiB)
  double* p = (double*)d_ws;
  int* idx = (int*)(p + BATCH * NCAND);

  score_kernel<<<BATCH * NCAND, 256, 0, stream>>>(x, w, p);
  rank_kernel<<<BATCH, 512, 0, stream>>>(p, idx);
  gather_kernel<<<BATCH * KSEL, 256, 0, stream>>>(x, idx, out);
}

// Round 2
// 435.842 us; speedup vs baseline: 1.0193x; 1.0193x over previous
//
#include <hip/hip_runtime.h>

// Problem constants (fixed by setup_inputs)
#define BATCH 32
#define NCAND 512
#define HH 64
#define WW 64
#define KSEL 256
#define HW (HH * WW)          // 4096 floats per image
#define OUT_H (HH - 2)        // 62
#define OUT_W (WW - 2)        // 62

// ---------------------------------------------------------------------------
// Kernel 1: per-image curvature score, rolling row-conv formulation.
// Filter rows: row0 = row2 = [-1/16, 5/16, -1/16], row1 = [5/16, -1, 5/16].
// Per input row r and column j:
//   h    = x[r][j] + x[r][j+2]
//   A(r) = wa0*h + wa1*x[r][j+1]     (wa0=-1/16, wa1=5/16)
//   B(r) = wb0*h + wb1*x[r][j+1]     (wb0= 5/16, wb1=-1)
// Output pixel: s(i,j) = A(i) + B(i+1) + A(i+2);  score = sum |s|.
// One block (256 thr = 4 waves) per image; wave w owns output-row strip
// 16w..16w+15 (wave 3: 14 rows); lane j owns output column j (62 cols).
// All conv arithmetic in f64 so ordering matches the f64 numpy reference
// exactly (output is an exact gather -> any rank swap = huge absmax).
// ---------------------------------------------------------------------------
__global__ __launch_bounds__(256) void score_kernel(
    const float* __restrict__ x, const float* __restrict__ w,
    double* __restrict__ p) {
  __shared__ float tile[HW];              // 16 KiB
  __shared__ double partial[4];

  const int img = blockIdx.x;             // b*NCAND + n
  const int tid = threadIdx.x;

  // Coalesced float4 staging: 1024 float4 / 256 threads = 4 each.
  const float4* src4 = (const float4*)(x + (size_t)img * HW);
  float4* t4 = (float4*)tile;
#pragma unroll
  for (int i = 0; i < 4; ++i) t4[i * 256 + tid] = src4[i * 256 + tid];

  // Uniform weight loads (exact values: -1/16, 5/16, -1).
  const double wa0 = (double)w[0];
  const double wa1 = (double)w[1];
  const double wb0 = (double)w[3];
  const double wb1 = (double)w[4];

  __syncthreads();

  const int wave = tid >> 6;
  const int lane = tid & 63;
  const int j = lane < OUT_W ? lane : (OUT_W - 1);  // clamp lanes 62,63
  const int i0 = wave * 16;                         // first output row
  const int nout = (wave == 3) ? 14 : 16;           // output rows this wave
  const float* tj = tile + i0 * WW + j;

  double acc = 0.0;

  // Rolling window: Ai = A(i), Ai1 = A(i+1), Bi1 = B(i+1).
  double Ai, Ai1, Bi1;
  {
    float f0 = tj[0], f1 = tj[1], f2 = tj[2];
    double h = (double)f0 + (double)f2, m = (double)f1;
    Ai = fma(h, wa0, m * wa1);
  }
  {
    float f0 = tj[WW], f1 = tj[WW + 1], f2 = tj[WW + 2];
    double h = (double)f0 + (double)f2, m = (double)f1;
    Ai1 = fma(h, wa0, m * wa1);
    Bi1 = fma(h, wb0, m * wb1);
  }
#pragma unroll
  for (int r = 0; r < 16; ++r) {
    if (r < nout) {                        // wave-uniform predicate
      const float* row = tj + (r + 2) * WW;
      float f0 = row[0], f1 = row[1], f2 = row[2];
      double h = (double)f0 + (double)f2, m = (double)f1;
      double A2 = fma(h, wa0, m * wa1);
      double B2 = fma(h, wb0, m * wb1);
      double s = Ai + Bi1 + A2;
      acc += fabs(s);
      Ai = Ai1; Ai1 = A2; Bi1 = B2;
    }
  }

  if (lane >= OUT_W) acc = 0.0;            // clamped duplicate lanes

  // Wave reduce then cross-wave via LDS.
#pragma unroll
  for (int off = 32; off > 0; off >>= 1) acc += __shfl_down(acc, off, 64);
  if (lane == 0) partial[wave] = acc;
  __syncthreads();
  if (tid == 0) p[img] = partial[0] + partial[1] + partial[2] + partial[3];
}

// ---------------------------------------------------------------------------
// Kernel 2: per-batch exact top-k ordering via rank computation.
// rank(n) = #{m : p[m] > p[n]  or  (p[m] == p[n] and m < n)}  -> lax.top_k
// descending, index-stable semantics.
// ---------------------------------------------------------------------------
__global__ __launch_bounds__(512) void rank_kernel(
    const double* __restrict__ p, int* __restrict__ idx) {
  __shared__ double sp[NCAND];            // 4 KiB
  const int b = blockIdx.x;
  const int n = threadIdx.x;
  sp[n] = p[(size_t)b * NCAND + n];
  __syncthreads();
  const double pn = sp[n];
  int rank = 0;
#pragma unroll 8
  for (int m = 0; m < NCAND; ++m) {
    const double pm = sp[m];              // broadcast read, no conflict
    rank += (pm > pn) || (pm == pn && m < n);
  }
  if (rank < KSEL) idx[b * KSEL + rank] = n;
}

// ---------------------------------------------------------------------------
// Kernel 3: gather selected images. One block per output slot (b,r);
// coalesced float4 copy of 16 KiB.
// ---------------------------------------------------------------------------
__global__ __launch_bounds__(256) void gather_kernel(
    const float* __restrict__ x, const int* __restrict__ idx,
    float* __restrict__ out) {
  const int o = blockIdx.x;               // b*KSEL + r
  const int b = o / KSEL;
  const int n = idx[o];                   // uniform load
  const float4* src = (const float4*)(x + ((size_t)b * NCAND + n) * HW);
  float4* dst = (float4*)(out + (size_t)o * HW);
  const int tid = threadIdx.x;
#pragma unroll
  for (int i = 0; i < 4; ++i) dst[i * 256 + tid] = src[i * 256 + tid];
}

extern "C" void kernel_launch(void* const* d_in, const int* in_sizes, int n_in,
                              void* d_out, int out_size, void* d_ws,
                              size_t ws_size, hipStream_t stream) {
  const float* x = (const float*)d_in[0];
  const float* w = (const float*)d_in[1];
  float* out = (float*)d_out;

  // Workspace layout: scores (16384 f64 = 128 KiB) then idx (8192 i32 = 32 KiB)
  double* p = (double*)d_ws;
  int* idx = (int*)(p + BATCH * NCAND);

  score_kernel<<<BATCH * NCAND, 256, 0, stream>>>(x, w, p);
  rank_kernel<<<BATCH, 512, 0, stream>>>(p, idx);
  gather_kernel<<<BATCH * KSEL, 256, 0, stream>>>(x, idx, out);
}